// Round 2
// baseline (168.163 us; speedup 1.0000x reference)
//
#include <hip/hip_runtime.h>

// RuleClassifierSNN — forward only.
//  * spike(post-reset v) == 0 always  -> W_rec vanishes in forward.
//  * layer-0 drive is a V=128-entry lookup table (0.2f-folded).
//  * layer-1 GEMM: s0 in {0,1} stored as i8; W as 2-plane i8 fixed point
//    (q1 + q2/252 at per-row scale) -> exact i32 accumulate, ~2^-19 residual.

#define T_STEPS 256
#define B_SZ    2048
#define H_SZ    128
#define V_SZ    128
#define E_SZ    64
#define C_SZ    12

typedef __attribute__((ext_vector_type(4))) int   i32x4;
typedef __attribute__((ext_vector_type(4))) float f32x4;

#define OMB  0.2f
#define BETA 0.8f

// ---------------------------------------------------------------------------
// Kernel 1: layer-0 lookup table. table0[v][h] = 0.2*((emb[v]@W_in.T+b_in)@W_lif0.T+b_lif0)
__global__ void k_table(const float* __restrict__ emb, const float* __restrict__ W_in,
                        const float* __restrict__ b_in, const float* __restrict__ W_lif0,
                        const float* __restrict__ b_lif0, float* __restrict__ table0p) {
  __shared__ float x1s[H_SZ];
  int v = blockIdx.x, h = threadIdx.x;
  float s = b_in[h];
  const float* er = emb + v * E_SZ;
  const float* wr = W_in + h * E_SZ;
#pragma unroll 8
  for (int e = 0; e < E_SZ; ++e) s += er[e] * wr[e];
  x1s[h] = s;
  __syncthreads();
  float t0 = b_lif0[h];
  const float* w0 = W_lif0 + h * H_SZ;
#pragma unroll 8
  for (int i = 0; i < H_SZ; ++i) t0 += x1s[i] * w0[i];
  table0p[v * H_SZ + h] = OMB * t0;
}

// ---------------------------------------------------------------------------
// Kernel 2: layer-0 LIF scan -> i8 spikes in MFMA-A(16x16x64 i8) swizzled layout.
// Byte address of (t, b=btile*16+bl, h=kt*64+quad*16+j):
//   t*B*H + btile*2048 + kt*1024 + quad*256 + bl*16 + j
// Wave covers 4 b x 16 j  -> 64 contiguous bytes per store instr.
__global__ void k_layer0(const int* __restrict__ ids, const float* __restrict__ table0p,
                         signed char* __restrict__ s0s) {
  int u = blockIdx.x * blockDim.x + threadIdx.x;   // [0, 262144)
  int lane = u & 63;
  int j = lane & 15, b_off = lane >> 4;
  int w = u >> 6;
  int quad = w & 3, kt = (w >> 2) & 1, bgrp = (w >> 3) & 3, btile = w >> 5;
  int b = btile * 16 + bgrp * 4 + b_off;
  int h = kt * 64 + quad * 16 + j;
  const int* idrow = ids + b * T_STEPS;
  signed char* p = s0s + (btile * 2048 + kt * 1024 + quad * 256 + (bgrp * 4 + b_off) * 16 + j);
  float v = 0.0f;
  float tv = table0p[idrow[0] * H_SZ + h];
  for (int t = 0; t < T_STEPS; ++t) {
    float tvn = 0.0f;
    if (t + 1 < T_STEPS) tvn = table0p[idrow[t + 1] * H_SZ + h];
    v = fmaf(BETA, v, tv);
    bool sp = v >= 1.0f;
    p[(size_t)t * (B_SZ * H_SZ)] = sp ? 1 : 0;
    if (sp) v = 0.0f;
    tv = tvn;
  }
}

// ---------------------------------------------------------------------------
// Kernel 3: layer-1 scan. 256 blocks x 4 waves; wave = 16b x 16n tile, K=128
// via 2x mfma_i32_16x16x64_i8 per plane. W 2-plane i8 in registers; v1/acc in
// MFMA C-layout registers for all 256 steps. Depth-8 prefetch ring (~900cyc cover).
__launch_bounds__(256, 1)
__global__ void k_scan(const signed char* __restrict__ s0s,
                       const float* __restrict__ W1, const float* __restrict__ b_lif,
                       float* __restrict__ accbuf) {
  int bid = blockIdx.x;
  int btile = (bid & 7) * 16 + (bid >> 4);   // [0,128)
  int nhalf = (bid >> 3) & 1;
  int wid = threadIdx.x >> 6, lane = threadIdx.x & 63;
  int nl = lane & 15, quad = lane >> 4;
  int n = nhalf * 64 + wid * 16 + nl;        // output h == W row

  // ---- per-row 2-plane i8 quantization of 0.2*W_lif1[n,:] ----
  const float* wrow = W1 + n * H_SZ;
  const float4* w4 = (const float4*)wrow;
  float mx = 1e-20f;
#pragma unroll
  for (int i = 0; i < 32; ++i) {
    float4 x = w4[i];
    mx = fmaxf(mx, fmaxf(fmaxf(fabsf(x.x), fabsf(x.y)), fmaxf(fabsf(x.z), fabsf(x.w))));
  }
  mx *= OMB;
  float S1 = 126.0f / mx, inv1 = 1.0f / S1;
  float S2 = S1 * 252.0f, inv2 = 1.0f / S2;

  i32x4 Wq1[2], Wq2[2];
#pragma unroll
  for (int kt = 0; kt < 2; ++kt) {
    int q1w[4] = {0, 0, 0, 0}, q2w[4] = {0, 0, 0, 0};
#pragma unroll
    for (int jj = 0; jj < 16; ++jj) {
      int k = kt * 64 + quad * 16 + jj;
      float ww = OMB * wrow[k];
      float q1 = rintf(ww * S1);
      float r  = fmaf(-q1, inv1, ww);
      float q2 = rintf(r * S2);
      q1w[jj >> 2] |= ((int)q1 & 0xFF) << ((jj & 3) * 8);
      q2w[jj >> 2] |= ((int)q2 & 0xFF) << ((jj & 3) * 8);
    }
    Wq1[kt] = (i32x4){q1w[0], q1w[1], q1w[2], q1w[3]};
    Wq2[kt] = (i32x4){q2w[0], q2w[1], q2w[2], q2w[3]};
  }
  float b1v = OMB * b_lif[H_SZ + n];

  const i32x4* As = (const i32x4*)s0s;
  const int tstride = 16384;                 // 256KB / 16B
  int off0 = btile * 128 + quad * 16 + nl;   // kt=0 fragment (16B units)
  int off1 = off0 + 64;                      // kt=1

  f32x4 v1 = {0.f, 0.f, 0.f, 0.f};
  f32x4 acc = {0.f, 0.f, 0.f, 0.f};

  constexpr int D = 8;                       // prefetch depth (steps)
  i32x4 A0[D], A1[D];
#pragma unroll
  for (int s = 0; s < D; ++s) { A0[s] = As[s * tstride + off0]; A1[s] = As[s * tstride + off1]; }

  for (int t = 0; t < T_STEPS; t += D) {
#pragma unroll
    for (int s = 0; s < D; ++s) {
      i32x4 P1 = {0, 0, 0, 0}, P2 = {0, 0, 0, 0};
      P1 = __builtin_amdgcn_mfma_i32_16x16x64_i8(A0[s], Wq1[0], P1, 0, 0, 0);
      P1 = __builtin_amdgcn_mfma_i32_16x16x64_i8(A1[s], Wq1[1], P1, 0, 0, 0);
      P2 = __builtin_amdgcn_mfma_i32_16x16x64_i8(A0[s], Wq2[0], P2, 0, 0, 0);
      P2 = __builtin_amdgcn_mfma_i32_16x16x64_i8(A1[s], Wq2[1], P2, 0, 0, 0);
      int tn = t + D + s;
      if (tn < T_STEPS) { A0[s] = As[tn * tstride + off0]; A1[s] = As[tn * tstride + off1]; }
#pragma unroll
      for (int r = 0; r < 4; ++r) {
        float cur = fmaf((float)P2[r], inv2, fmaf((float)P1[r], inv1, b1v));
        float nv  = fmaf(BETA, v1[r], cur);
        bool sp   = nv >= 1.0f;
        acc[r] += sp ? 1.0f : 0.0f;
        v1[r]   = sp ? 0.0f : nv;
      }
    }
  }
#pragma unroll
  for (int r = 0; r < 4; ++r) {
    int b = btile * 16 + quad * 4 + r;
    accbuf[b * H_SZ + n] = acc[r];
  }
}

// ---------------------------------------------------------------------------
// Kernel 4: logits = (acc/256) @ W_cls.T + b_cls
__global__ void k_logits(const float* __restrict__ accbuf, const float* __restrict__ Wc,
                         const float* __restrict__ bc, float* __restrict__ out) {
  int u = blockIdx.x * blockDim.x + threadIdx.x;
  if (u >= B_SZ * C_SZ) return;
  int b = u / C_SZ, c = u - b * C_SZ;
  const float4* a4 = (const float4*)(accbuf + b * H_SZ);
  const float4* w4 = (const float4*)(Wc + c * H_SZ);
  float s = bc[c];
#pragma unroll
  for (int i = 0; i < H_SZ / 4; ++i) {
    float4 a = a4[i], wv = w4[i];
    s += (a.x * 0.00390625f) * wv.x + (a.y * 0.00390625f) * wv.y +
         (a.z * 0.00390625f) * wv.z + (a.w * 0.00390625f) * wv.w;
  }
  out[u] = s;
}

// ---------------------------------------------------------------------------
extern "C" void kernel_launch(void* const* d_in, const int* in_sizes, int n_in,
                              void* d_out, int out_size, void* d_ws, size_t ws_size,
                              hipStream_t stream) {
  (void)in_sizes; (void)n_in; (void)out_size; (void)ws_size;
  const int*   ids   = (const int*)d_in[0];
  const float* emb   = (const float*)d_in[1];
  const float* W_in  = (const float*)d_in[2];
  const float* b_in  = (const float*)d_in[3];
  const float* W_lif = (const float*)d_in[4];
  const float* b_lif = (const float*)d_in[5];
  // d_in[6] (W_rec) provably unused in forward
  const float* W_cls = (const float*)d_in[7];
  const float* b_cls = (const float*)d_in[8];
  float* out = (float*)d_out;

  char* ws = (char*)d_ws;
  signed char* s0s = (signed char*)ws;                       // 67,108,864 B
  float* table0p = (float*)(ws + 67108864);                  //     65,536 B
  float* accbuf  = (float*)(ws + 67108864 + 65536);          //  1,048,576 B

  k_table <<<V_SZ, H_SZ, 0, stream>>>(emb, W_in, b_in, W_lif, b_lif, table0p);
  k_layer0<<<(B_SZ * H_SZ) / 256, 256, 0, stream>>>(ids, table0p, s0s);
  k_scan  <<<256, 256, 0, stream>>>(s0s, W_lif + H_SZ * H_SZ, b_lif, accbuf);
  k_logits<<<(B_SZ * C_SZ + 255) / 256, 256, 0, stream>>>(accbuf, W_cls, b_cls, out);
}

// Round 3
// 141.718 us; speedup vs baseline: 1.1866x; 1.1866x over previous
//
#include <hip/hip_runtime.h>

// RuleClassifierSNN — forward only.
//  * spike(post-reset v) == 0 always  -> W_rec vanishes in forward.
//  * layer-0 drive is a V=128-entry lookup table (0.2f-folded).
//  * layer-1 GEMM: s0 in {0,1} stored as i8; W as 2-plane i8 fixed point
//    (q1 + q2/252 at per-row scale) -> exact i32 accumulate, ~2^-19 residual.
//    Plane combine P = 252*P1 + P2 is exact in i32 (|P| < 2^23).

#define T_STEPS 256
#define B_SZ    2048
#define H_SZ    128
#define V_SZ    128
#define E_SZ    64
#define C_SZ    12

typedef __attribute__((ext_vector_type(4))) int   i32x4;
typedef __attribute__((ext_vector_type(4))) float f32x4;

#define OMB  0.2f
#define BETA 0.8f

// ws layout
#define S0_BYTES   67108864          // 256*2048*128 i8
#define S0_PAD     2097152           // 8 extra t-steps (branch-free prefetch)
#define TB_OFF     (S0_BYTES + S0_PAD)
#define ACC_OFF    (TB_OFF + 65536)

// ---------------------------------------------------------------------------
// Kernel 1: layer-0 lookup table. table0[v][h] = 0.2*((emb[v]@W_in.T+b_in)@W_lif0.T+b_lif0)
__global__ void k_table(const float* __restrict__ emb, const float* __restrict__ W_in,
                        const float* __restrict__ b_in, const float* __restrict__ W_lif0,
                        const float* __restrict__ b_lif0, float* __restrict__ table0p) {
  __shared__ float x1s[H_SZ];
  int v = blockIdx.x, h = threadIdx.x;
  float s = b_in[h];
  const float* er = emb + v * E_SZ;
  const float* wr = W_in + h * E_SZ;
#pragma unroll 8
  for (int e = 0; e < E_SZ; ++e) s += er[e] * wr[e];
  x1s[h] = s;
  __syncthreads();
  float t0 = b_lif0[h];
  const float* w0 = W_lif0 + h * H_SZ;
#pragma unroll 8
  for (int i = 0; i < H_SZ; ++i) t0 += x1s[i] * w0[i];
  table0p[v * H_SZ + h] = OMB * t0;
}

// ---------------------------------------------------------------------------
// Kernel 2: layer-0 LIF scan with LDS-resident table half + ids rows.
// Grid: 1024 blocks x 256 thr. Block (bg, kt): 4 batch rows (bg*4..+3),
// h-half kt (h = kt*64 + hh). 32KB table slice + 4KB ids -> 4 blocks/CU.
// Output layout = MFMA-A(16x16x64 i8) swizzle:
//   byte(t,b,h) = t*B*H + (b>>4)*2048 + (h>>6)*1024 + ((h>>4)&3)*256 + (b&15)*16 + (h&15)
__global__ void k_layer0(const int* __restrict__ ids, const float* __restrict__ table0p,
                         signed char* __restrict__ s0s) {
  __shared__ float tbl[V_SZ * 64];       // [v][hh]  32 KB
  __shared__ int   ids_s[4 * 260];       // [bl][t], padded to 260 (tail guard)
  int tid = threadIdx.x;
  int bg = blockIdx.x >> 1;              // [0,512): group of 4 batch rows
  int kt = blockIdx.x & 1;               // h-half
  int h0 = kt * 64;

  // stage table slice: tbl[v*64+hh] = table0p[v*128 + h0 + hh]
#pragma unroll
  for (int i = 0; i < 32; ++i) {
    int idx = tid + i * 256;
    tbl[idx] = table0p[(idx >> 6) * H_SZ + h0 + (idx & 63)];
  }
  // stage 4 rows of ids (contiguous: ids[bg*1024 .. +1024))
#pragma unroll
  for (int i = 0; i < 4; ++i) {
    int idx = tid + i * 256;
    ids_s[(idx >> 8) * 260 + (idx & 255)] = ids[bg * 1024 + idx];
  }
  if (tid < 16) ids_s[(tid >> 2) * 260 + 256 + (tid & 3)] = 0;  // tail guard
  __syncthreads();

  int bl = tid >> 6, hh = tid & 63;
  int quad = hh >> 4, j = hh & 15;
  int bl16 = (bg & 3) * 4 + bl;
  signed char* p = s0s + ((size_t)(bg >> 2) * 2048 + kt * 1024 + quad * 256 + bl16 * 16 + j);
  const int idbase = bl * 260;

  float v = 0.0f;
  float tvn[4];
#pragma unroll
  for (int d = 0; d < 4; ++d) tvn[d] = tbl[ids_s[idbase + d] * 64 + hh];

  for (int t = 0; t < T_STEPS; t += 4) {
#pragma unroll
    for (int s = 0; s < 4; ++s) {
      float tv = tvn[s];
      int idn = ids_s[idbase + t + s + 4];     // <=259, guarded by pad
      tvn[s] = tbl[idn * 64 + hh];
      v = fmaf(BETA, v, tv);
      bool sp = v >= 1.0f;
      p[(size_t)(t + s) * (B_SZ * H_SZ)] = sp ? 1 : 0;
      v = sp ? 0.0f : v;
    }
  }
}

// ---------------------------------------------------------------------------
// Kernel 3: layer-1 scan. 256 blocks x 4 waves; wave = 16b x 16n, K=128 via
// 2x mfma_i32_16x16x64_i8 per plane. Branch-free D=8 ring (pad-backed),
// explicit one-step MFMA pipeline so MFMA latency is off the v1 chain.
__launch_bounds__(256, 1)
__global__ void k_scan(const signed char* __restrict__ s0s,
                       const float* __restrict__ W1, const float* __restrict__ b_lif,
                       float* __restrict__ accbuf) {
  int bid = blockIdx.x;
  int btile = (bid & 7) * 16 + (bid >> 4);   // [0,128)
  int nhalf = (bid >> 3) & 1;
  int wid = threadIdx.x >> 6, lane = threadIdx.x & 63;
  int nl = lane & 15, quad = lane >> 4;
  int n = nhalf * 64 + wid * 16 + nl;        // output h == W row

  // ---- per-row 2-plane i8 quantization of 0.2*W_lif1[n,:] ----
  const float* wrow = W1 + n * H_SZ;
  const float4* w4 = (const float4*)wrow;
  float mx = 1e-20f;
#pragma unroll
  for (int i = 0; i < 32; ++i) {
    float4 x = w4[i];
    mx = fmaxf(mx, fmaxf(fmaxf(fabsf(x.x), fabsf(x.y)), fmaxf(fabsf(x.z), fabsf(x.w))));
  }
  mx *= OMB;
  float S1 = 126.0f / mx, inv1 = 1.0f / S1;
  float S2 = S1 * 252.0f, inv2 = 1.0f / S2;

  i32x4 Wq1[2], Wq2[2];
#pragma unroll
  for (int kt = 0; kt < 2; ++kt) {
    int q1w[4] = {0, 0, 0, 0}, q2w[4] = {0, 0, 0, 0};
#pragma unroll
    for (int jj = 0; jj < 16; ++jj) {
      int k = kt * 64 + quad * 16 + jj;
      float ww = OMB * wrow[k];
      float q1 = rintf(ww * S1);
      float r  = fmaf(-q1, inv1, ww);
      float q2 = rintf(r * S2);
      q1w[jj >> 2] |= ((int)q1 & 0xFF) << ((jj & 3) * 8);
      q2w[jj >> 2] |= ((int)q2 & 0xFF) << ((jj & 3) * 8);
    }
    Wq1[kt] = (i32x4){q1w[0], q1w[1], q1w[2], q1w[3]};
    Wq2[kt] = (i32x4){q2w[0], q2w[1], q2w[2], q2w[3]};
  }
  float b1v = OMB * b_lif[H_SZ + n];

  const i32x4* As = (const i32x4*)s0s;
  const int tstride = 16384;                 // 256KB / 16B
  int off0 = btile * 128 + quad * 16 + nl;
  int off1 = off0 + 64;

  f32x4 v1 = {0.f, 0.f, 0.f, 0.f};
  i32x4 cnt = {0, 0, 0, 0};
  const i32x4 Z = {0, 0, 0, 0};

  constexpr int D = 8;
  i32x4 A0[D], A1[D];
#pragma unroll
  for (int s = 0; s < D; ++s) { A0[s] = As[s * tstride + off0]; A1[s] = As[s * tstride + off1]; }

  // prologue: P for step 0
  i32x4 P1c = __builtin_amdgcn_mfma_i32_16x16x64_i8(A0[0], Wq1[0], Z, 0, 0, 0);
  P1c       = __builtin_amdgcn_mfma_i32_16x16x64_i8(A1[0], Wq1[1], P1c, 0, 0, 0);
  i32x4 P2c = __builtin_amdgcn_mfma_i32_16x16x64_i8(A0[0], Wq2[0], Z, 0, 0, 0);
  P2c       = __builtin_amdgcn_mfma_i32_16x16x64_i8(A1[0], Wq2[1], P2c, 0, 0, 0);

  for (int t = 0; t < T_STEPS; t += D) {
#pragma unroll
    for (int s = 0; s < D; ++s) {
      // prefetch global for step t+s+D (pad region beyond T: harmless)
      size_t tn = (size_t)(t + s + D);
      i32x4 na0 = As[tn * tstride + off0];
      i32x4 na1 = As[tn * tstride + off1];
      // MFMA for NEXT step (t+s+1) from ring slot (s+1)%D
      int s1 = (s + 1) & (D - 1);
      i32x4 P1n = __builtin_amdgcn_mfma_i32_16x16x64_i8(A0[s1], Wq1[0], Z, 0, 0, 0);
      P1n       = __builtin_amdgcn_mfma_i32_16x16x64_i8(A1[s1], Wq1[1], P1n, 0, 0, 0);
      i32x4 P2n = __builtin_amdgcn_mfma_i32_16x16x64_i8(A0[s1], Wq2[0], Z, 0, 0, 0);
      P2n       = __builtin_amdgcn_mfma_i32_16x16x64_i8(A1[s1], Wq2[1], P2n, 0, 0, 0);
      // epilogue for current step (uses P1c/P2c)
#pragma unroll
      for (int r = 0; r < 4; ++r) {
        int   P   = P1c[r] * 252 + P2c[r];           // exact, |P| < 2^23
        float cur = fmaf((float)P, inv2, b1v);
        float nv  = fmaf(BETA, v1[r], cur);
        bool  sp  = nv >= 1.0f;
        cnt[r] += sp ? 1 : 0;
        v1[r]   = sp ? 0.0f : nv;
      }
      P1c = P1n; P2c = P2n;
      A0[s] = na0; A1[s] = na1;
    }
  }
#pragma unroll
  for (int r = 0; r < 4; ++r) {
    int b = btile * 16 + quad * 4 + r;
    accbuf[b * H_SZ + n] = (float)cnt[r];
  }
}

// ---------------------------------------------------------------------------
// Kernel 4: logits = (acc/256) @ W_cls.T + b_cls
__global__ void k_logits(const float* __restrict__ accbuf, const float* __restrict__ Wc,
                         const float* __restrict__ bc, float* __restrict__ out) {
  int u = blockIdx.x * blockDim.x + threadIdx.x;
  if (u >= B_SZ * C_SZ) return;
  int b = u / C_SZ, c = u - b * C_SZ;
  const float4* a4 = (const float4*)(accbuf + b * H_SZ);
  const float4* w4 = (const float4*)(Wc + c * H_SZ);
  float s = bc[c];
#pragma unroll
  for (int i = 0; i < H_SZ / 4; ++i) {
    float4 a = a4[i], wv = w4[i];
    s += (a.x * 0.00390625f) * wv.x + (a.y * 0.00390625f) * wv.y +
         (a.z * 0.00390625f) * wv.z + (a.w * 0.00390625f) * wv.w;
  }
  out[u] = s;
}

// ---------------------------------------------------------------------------
extern "C" void kernel_launch(void* const* d_in, const int* in_sizes, int n_in,
                              void* d_out, int out_size, void* d_ws, size_t ws_size,
                              hipStream_t stream) {
  (void)in_sizes; (void)n_in; (void)out_size; (void)ws_size;
  const int*   ids   = (const int*)d_in[0];
  const float* emb   = (const float*)d_in[1];
  const float* W_in  = (const float*)d_in[2];
  const float* b_in  = (const float*)d_in[3];
  const float* W_lif = (const float*)d_in[4];
  const float* b_lif = (const float*)d_in[5];
  // d_in[6] (W_rec) provably unused in forward
  const float* W_cls = (const float*)d_in[7];
  const float* b_cls = (const float*)d_in[8];
  float* out = (float*)d_out;

  char* ws = (char*)d_ws;
  signed char* s0s = (signed char*)ws;            // 67 MB + 2 MB prefetch pad
  float* table0p = (float*)(ws + TB_OFF);         // 64 KB
  float* accbuf  = (float*)(ws + ACC_OFF);        // 1 MB

  k_table <<<V_SZ, H_SZ, 0, stream>>>(emb, W_in, b_in, W_lif, b_lif, table0p);
  k_layer0<<<1024, 256, 0, stream>>>(ids, table0p, s0s);
  k_scan  <<<256, 256, 0, stream>>>(s0s, W_lif + H_SZ * H_SZ, b_lif, accbuf);
  k_logits<<<(B_SZ * C_SZ + 255) / 256, 256, 0, stream>>>(accbuf, W_cls, b_cls, out);
}